// Round 1
// baseline (676.654 us; speedup 1.0000x reference)
//
#include <hip/hip_runtime.h>

#define B_  8
#define S_  2048
#define D_  128
#define H_  4
#define HD_ 32
#define BH_ (B_ * H_)

// ---------------------------------------------------------------------------
// Kernel A: qkv = x @ w_attn  (M=B*S=16384, K=128, N=384)
// Writes Q,K,V scattered into [B*H, S, HD] layout.
// Block: 384 threads (1 col each), 16 rows of x staged in LDS.
// ---------------------------------------------------------------------------
__global__ __launch_bounds__(384) void qkv_kernel(const float* __restrict__ x,
                                                  const float* __restrict__ w,
                                                  float* __restrict__ Q,
                                                  float* __restrict__ K,
                                                  float* __restrict__ V) {
    __shared__ float xs[16][128];
    const int row0 = blockIdx.x * 16;          // flat row = b*S + s (never straddles b)
    const int tid = threadIdx.x;

    for (int i = tid; i < 16 * 128; i += 384) {
        xs[i >> 7][i & 127] = x[row0 * 128 + i];
    }
    __syncthreads();

    const int col = tid;                        // 0..383
    float acc[16];
#pragma unroll
    for (int r = 0; r < 16; ++r) acc[r] = 0.f;

    for (int k = 0; k < 128; ++k) {
        float wv = w[k * 384 + col];            // coalesced across threads
#pragma unroll
        for (int r = 0; r < 16; ++r) acc[r] += xs[r][k] * wv;  // LDS broadcast
    }

    const int which = col >> 7;                 // 0=Q,1=K,2=V
    const int c = col & 127;
    const int h = c >> 5, d = c & 31;
    float* dst = (which == 0) ? Q : (which == 1) ? K : V;
#pragma unroll
    for (int r = 0; r < 16; ++r) {
        int fr = row0 + r;
        int b = fr >> 11;                       // /S_
        int s = fr & (S_ - 1);
        dst[(((b * H_) + h) * S_ + s) * HD_ + d] = acc[r];
    }
}

// ---------------------------------------------------------------------------
// Kernel B: causal flash attention. One thread per query row.
// Block: 256 threads = 256 consecutive q rows of one (b,h).
// K/V tiles (64 x 32 fp32) staged in LDS; online softmax in registers.
// ---------------------------------------------------------------------------
__global__ __launch_bounds__(256) void attn_kernel(const float* __restrict__ Q,
                                                   const float* __restrict__ K,
                                                   const float* __restrict__ V,
                                                   float* __restrict__ O) {
    const int qblocks = S_ / 256;               // 8
    const int bh = blockIdx.x / qblocks;
    const int qt = blockIdx.x % qblocks;
    const int q  = qt * 256 + threadIdx.x;

    const float scale = 0.17677669529663687f;   // 1/sqrt(32)

    float qv[HD_];
    const float* qptr = Q + (bh * S_ + q) * HD_;
#pragma unroll
    for (int j = 0; j < HD_; ++j) qv[j] = qptr[j] * scale;

    float o[HD_];
#pragma unroll
    for (int j = 0; j < HD_; ++j) o[j] = 0.f;
    float m = -1e30f, l = 0.f;

    __shared__ float Ks[64][HD_];
    __shared__ float Vs[64][HD_];

    const int ntile = (qt * 256 + 256) / 64;    // k-tiles covering k <= q_max

    for (int t = 0; t < ntile; ++t) {
        __syncthreads();
        for (int i = threadIdx.x; i < 64 * HD_; i += 256) {
            int kk = i >> 5, j = i & 31;
            int kg = t * 64 + kk;
            Ks[kk][j] = K[(bh * S_ + kg) * HD_ + j];
            Vs[kk][j] = V[(bh * S_ + kg) * HD_ + j];
        }
        __syncthreads();

        int kmax = q - t * 64 + 1;              // #valid k in this tile for this thread
        if (kmax > 64) kmax = 64;
        for (int kk = 0; kk < kmax; ++kk) {
            float s = 0.f;
#pragma unroll
            for (int j = 0; j < HD_; ++j) s += qv[j] * Ks[kk][j];
            if (s > m) {                        // rare rescale path
                float corr = __expf(m - s);
                l *= corr;
#pragma unroll
                for (int j = 0; j < HD_; ++j) o[j] *= corr;
                m = s;
            }
            float p = __expf(s - m);
            l += p;
#pragma unroll
            for (int j = 0; j < HD_; ++j) o[j] += p * Vs[kk][j];
        }
    }

    const float inv = 1.f / l;
    const int b = bh >> 2, h = bh & 3;          // H_=4
    float* optr = O + (b * S_ + q) * D_ + h * HD_;
#pragma unroll
    for (int j = 0; j < HD_; ++j) optr[j] = o[j] * inv;
}

// ---------------------------------------------------------------------------
// Kernel C: out = attn_out @ w_proj  (M=16384, K=128, N=128)
// ---------------------------------------------------------------------------
__global__ __launch_bounds__(128) void proj_kernel(const float* __restrict__ A,
                                                   const float* __restrict__ W,
                                                   float* __restrict__ out) {
    __shared__ float xs[16][128];
    const int row0 = blockIdx.x * 16;
    const int tid = threadIdx.x;

    for (int i = tid; i < 16 * 128; i += 128) {
        xs[i >> 7][i & 127] = A[row0 * 128 + i];
    }
    __syncthreads();

    const int col = tid;
    float acc[16];
#pragma unroll
    for (int r = 0; r < 16; ++r) acc[r] = 0.f;

    for (int k = 0; k < 128; ++k) {
        float wv = W[k * 128 + col];
#pragma unroll
        for (int r = 0; r < 16; ++r) acc[r] += xs[r][k] * wv;
    }

#pragma unroll
    for (int r = 0; r < 16; ++r) {
        out[(row0 + r) * 128 + col] = acc[r];
    }
}

// ---------------------------------------------------------------------------
extern "C" void kernel_launch(void* const* d_in, const int* in_sizes, int n_in,
                              void* d_out, int out_size, void* d_ws, size_t ws_size,
                              hipStream_t stream) {
    const float* x      = (const float*)d_in[0];
    const float* w_attn = (const float*)d_in[1];
    const float* w_proj = (const float*)d_in[2];
    float* out = (float*)d_out;

    const size_t NELEM = (size_t)BH_ * S_ * HD_;   // 2,097,152 floats = 8 MB
    float* Q  = (float*)d_ws;
    float* K  = Q + NELEM;
    float* V  = K + NELEM;
    float* AO = V + NELEM;                         // [B,S,D]

    qkv_kernel<<<(B_ * S_) / 16, 384, 0, stream>>>(x, w_attn, Q, K, V);
    attn_kernel<<<BH_ * (S_ / 256), 256, 0, stream>>>(Q, K, V, AO);
    proj_kernel<<<(B_ * S_) / 16, 128, 0, stream>>>(AO, w_proj, out);
}

// Round 2
// 101.190 us; speedup vs baseline: 6.6869x; 6.6869x over previous
//
#include <hip/hip_runtime.h>
#include <hip/hip_bf16.h>

#define B_  8
#define S_  2048
#define D_  128
#define H_  4
#define HD_ 32
#define BH_ (B_ * H_)

typedef __bf16 bf16x8 __attribute__((ext_vector_type(8)));
typedef float f32x16 __attribute__((ext_vector_type(16)));
typedef float f32x4  __attribute__((ext_vector_type(4)));

__device__ inline bf16x8 ld8(const __hip_bfloat16* p) {
    return *reinterpret_cast<const bf16x8*>(p);
}
__device__ inline unsigned cvtpk(float lo, float hi) {
    unsigned r;
    asm("v_cvt_pk_bf16_f32 %0, %1, %2" : "=v"(r) : "v"(lo), "v"(hi));
    return r;
}
// after: a = {a.lo32 | b.lo32-from-other-half}: ret0/ret1 of permlane32_swap
__device__ inline void swap32(unsigned &a, unsigned &b) {
    asm("v_permlane32_swap_b32 %0, %1" : "+v"(a), "+v"(b));
}

// ---------------------------------------------------------------------------
// Kernel A: qkv = x @ w_attn (fp32 compute), writes bf16:
//   Qb [BH][S][HD]  (pre-scaled by 1/sqrt(HD)*log2(e))
//   Kb [BH][S][HD]
//   Vt [BH][HD][S]  (transposed for PV MFMA A-operand)
// ---------------------------------------------------------------------------
__global__ __launch_bounds__(384) void qkv_kernel(const float* __restrict__ x,
                                                  const float* __restrict__ w,
                                                  __hip_bfloat16* __restrict__ Qb,
                                                  __hip_bfloat16* __restrict__ Kb,
                                                  __hip_bfloat16* __restrict__ Vt) {
    __shared__ float xs[16][128];
    const int row0 = blockIdx.x * 16;
    const int tid = threadIdx.x;

    for (int i = tid; i < 16 * 128; i += 384) {
        xs[i >> 7][i & 127] = x[row0 * 128 + i];
    }
    __syncthreads();

    const int col = tid;
    float acc[16];
#pragma unroll
    for (int r = 0; r < 16; ++r) acc[r] = 0.f;

    for (int k = 0; k < 128; ++k) {
        float wv = w[k * 384 + col];
#pragma unroll
        for (int r = 0; r < 16; ++r) acc[r] += xs[r][k] * wv;
    }

    const int which = col >> 7;                 // 0=Q,1=K,2=V
    const int c = col & 127;
    const int h = c >> 5, d = c & 31;
    const int b = row0 >> 11;
    const int s0 = row0 & (S_ - 1);
    const int bh = b * H_ + h;

    if (which == 0) {
        const float qs = 0.2550052557342824f;   // 1/sqrt(32) * log2(e)
#pragma unroll
        for (int r = 0; r < 16; ++r)
            Qb[(bh * S_ + s0 + r) * HD_ + d] = __float2bfloat16(acc[r] * qs);
    } else if (which == 1) {
#pragma unroll
        for (int r = 0; r < 16; ++r)
            Kb[(bh * S_ + s0 + r) * HD_ + d] = __float2bfloat16(acc[r]);
    } else {
        union { __hip_bfloat16 hh[16]; float4 f4[2]; } tmp;
#pragma unroll
        for (int r = 0; r < 16; ++r) tmp.hh[r] = __float2bfloat16(acc[r]);
        float4* dst = reinterpret_cast<float4*>(Vt + (bh * HD_ + d) * S_ + s0);
        dst[0] = tmp.f4[0];
        dst[1] = tmp.f4[1];
    }
}

// ---------------------------------------------------------------------------
// Kernel B: MFMA causal flash attention. 1 wave = 32 q-rows of one head.
// Swapped QK^T (S^T = K·Q^T) -> lane-local softmax; P^T->bf16 via
// cvt_pk + permlane32_swap; PV as O^T = V^T·P^T. No LDS.
// ---------------------------------------------------------------------------
__global__ __launch_bounds__(64) void fattn_kernel(
    const __hip_bfloat16* __restrict__ Qb,
    const __hip_bfloat16* __restrict__ Kb,
    const __hip_bfloat16* __restrict__ Vt,
    float* __restrict__ AO)                      // [B][S][D] fp32
{
    const int bh   = blockIdx.x & 31;            // head-major: head h -> XCD h%8
    const int qt   = blockIdx.x >> 5;            // 0..63
    const int lane = threadIdx.x;
    const int lq   = lane & 31;
    const int hi   = lane >> 5;
    const int q0   = qt * 32;

    // Q fragment (B-operand of QK^T): lane holds Q[q0+lq][8*hi+e]
    const __hip_bfloat16* qrow = Qb + (bh * S_ + q0 + lq) * HD_ + 8 * hi;
    const bf16x8 qf0 = ld8(qrow);
    const bf16x8 qf1 = ld8(qrow + 16);

    // K fragment (A-operand): lane holds K[kt*32+lq][8*hi+e]
    const __hip_bfloat16* kp = Kb + bh * S_ * HD_ + lq * HD_ + 8 * hi;
    // V^T fragment (A-operand of PV): lane holds Vt[lq][kt*32 + kb + 8*hi+e]
    const __hip_bfloat16* vp = Vt + (bh * HD_ + lq) * S_ + 8 * hi;

    f32x16 oacc = {};
    float m = -1e30f, lsum = 0.f;
    const int nt = qt + 1;

    bf16x8 kf0 = ld8(kp), kf1 = ld8(kp + 16);
    bf16x8 vf0 = ld8(vp), vf1 = ld8(vp + 16);

    for (int t = 0; t < nt; ++t) {
        const bf16x8 ck0 = kf0, ck1 = kf1, cv0 = vf0, cv1 = vf1;
        if (t + 1 < nt) {
            const __hip_bfloat16* kn = kp + (t + 1) * 32 * HD_;
            const __hip_bfloat16* vn = vp + (t + 1) * 32;
            kf0 = ld8(kn); kf1 = ld8(kn + 16);
            vf0 = ld8(vn); vf1 = ld8(vn + 16);
        }

        f32x16 s = {};
        s = __builtin_amdgcn_mfma_f32_32x32x16_bf16(ck0, qf0, s, 0, 0, 0);
        s = __builtin_amdgcn_mfma_f32_32x32x16_bf16(ck1, qf1, s, 0, 0, 0);

        if (t == qt) {                           // diagonal tile: mask k>q
#pragma unroll
            for (int r = 0; r < 16; ++r) {
                const int kloc = (r & 3) + 8 * (r >> 2) + 4 * hi;
                s[r] = (kloc > lq) ? -1e30f : s[r];
            }
        }

        float tmax = s[0];
#pragma unroll
        for (int r = 1; r < 16; ++r) tmax = fmaxf(tmax, s[r]);
        tmax = fmaxf(tmax, __shfl_xor(tmax, 32));
        const float mnew = fmaxf(m, tmax);
        const float corr = __builtin_amdgcn_exp2f(m - mnew);
        m = mnew;
        lsum *= corr;
#pragma unroll
        for (int r = 0; r < 16; ++r) oacc[r] *= corr;

#pragma unroll
        for (int r = 0; r < 16; ++r) {
            s[r] = __builtin_amdgcn_exp2f(s[r] - m);
            lsum += s[r];
        }

        // P^T -> bf16 B-fragments (T12: cvt_pk + permlane32_swap)
        unsigned a0 = cvtpk(s[0], s[1]),   a1 = cvtpk(s[2], s[3]);
        unsigned a2 = cvtpk(s[4], s[5]),   a3 = cvtpk(s[6], s[7]);
        swap32(a0, a2); swap32(a1, a3);    // a0=e01 a1=e23 a2=e45 a3=e67
        unsigned b0 = cvtpk(s[8], s[9]),   b1 = cvtpk(s[10], s[11]);
        unsigned b2 = cvtpk(s[12], s[13]), b3 = cvtpk(s[14], s[15]);
        swap32(b0, b2); swap32(b1, b3);

        union { unsigned u[4]; bf16x8 v; } pb0, pb1;
        pb0.u[0] = a0; pb0.u[1] = a1; pb0.u[2] = a2; pb0.u[3] = a3;
        pb1.u[0] = b0; pb1.u[1] = b1; pb1.u[2] = b2; pb1.u[3] = b3;

        oacc = __builtin_amdgcn_mfma_f32_32x32x16_bf16(cv0, pb0.v, oacc, 0, 0, 0);
        oacc = __builtin_amdgcn_mfma_f32_32x32x16_bf16(cv1, pb1.v, oacc, 0, 0, 0);
    }

    lsum += __shfl_xor(lsum, 32);
    const float inv = 1.f / lsum;
    const int b = bh >> 2, h = bh & 3;
    float* orow = AO + (b * S_ + q0 + lq) * D_ + h * HD_;
#pragma unroll
    for (int g = 0; g < 4; ++g) {
        f32x4 st;
#pragma unroll
        for (int j = 0; j < 4; ++j) st[j] = oacc[4 * g + j] * inv;
        *reinterpret_cast<f32x4*>(orow + 8 * g + 4 * hi) = st;   // d = 8g+4hi+j
    }
}

// ---------------------------------------------------------------------------
// Kernel C: out = AO @ w_proj (fp32 scalar)
// ---------------------------------------------------------------------------
__global__ __launch_bounds__(128) void proj_kernel(const float* __restrict__ A,
                                                   const float* __restrict__ W,
                                                   float* __restrict__ out) {
    __shared__ float xs[16][128];
    const int row0 = blockIdx.x * 16;
    const int tid = threadIdx.x;

    for (int i = tid; i < 16 * 128; i += 128) {
        xs[i >> 7][i & 127] = A[row0 * 128 + i];
    }
    __syncthreads();

    const int col = tid;
    float acc[16];
#pragma unroll
    for (int r = 0; r < 16; ++r) acc[r] = 0.f;

    for (int k = 0; k < 128; ++k) {
        float wv = W[k * 128 + col];
#pragma unroll
        for (int r = 0; r < 16; ++r) acc[r] += xs[r][k] * wv;
    }

#pragma unroll
    for (int r = 0; r < 16; ++r) {
        out[(row0 + r) * 128 + col] = acc[r];
    }
}

// ---------------------------------------------------------------------------
extern "C" void kernel_launch(void* const* d_in, const int* in_sizes, int n_in,
                              void* d_out, int out_size, void* d_ws, size_t ws_size,
                              hipStream_t stream) {
    const float* x      = (const float*)d_in[0];
    const float* w_attn = (const float*)d_in[1];
    const float* w_proj = (const float*)d_in[2];
    float* out = (float*)d_out;

    char* ws = (char*)d_ws;
    __hip_bfloat16* Qb = (__hip_bfloat16*)(ws);               // 4 MB
    __hip_bfloat16* Kb = (__hip_bfloat16*)(ws + (4  << 20));  // 4 MB
    __hip_bfloat16* Vt = (__hip_bfloat16*)(ws + (8  << 20));  // 4 MB
    float*          AO = (float*)        (ws + (12 << 20));   // 8 MB

    qkv_kernel<<<(B_ * S_) / 16, 384, 0, stream>>>(x, w_attn, Qb, Kb, Vt);
    fattn_kernel<<<BH_ * (S_ / 32), 64, 0, stream>>>(Qb, Kb, Vt, AO);
    proj_kernel<<<(B_ * S_) / 16, 128, 0, stream>>>(AO, w_proj, out);
}

// Round 3
// 68.479 us; speedup vs baseline: 9.8811x; 1.4777x over previous
//
#include <hip/hip_runtime.h>
#include <hip/hip_bf16.h>

#define B_  8
#define S_  2048
#define D_  128
#define H_  4
#define HD_ 32
#define BH_ (B_ * H_)

typedef __bf16 bf16x8 __attribute__((ext_vector_type(8)));
typedef float f32x16 __attribute__((ext_vector_type(16)));
typedef float f32x4  __attribute__((ext_vector_type(4)));

__device__ inline bf16x8 ld8(const __hip_bfloat16* p) {
    return *reinterpret_cast<const bf16x8*>(p);
}
__device__ inline unsigned cvtpk(float lo, float hi) {
    unsigned r;
    asm("v_cvt_pk_bf16_f32 %0, %1, %2" : "=v"(r) : "v"(lo), "v"(hi));
    return r;
}
__device__ inline void swap32(unsigned &a, unsigned &b) {
    asm("v_permlane32_swap_b32 %0, %1" : "+v"(a), "+v"(b));
}

// ---------------------------------------------------------------------------
// Convert x (fp32 [16384][128]) -> xb (bf16), 8 elems/thread.
// ---------------------------------------------------------------------------
__global__ __launch_bounds__(256) void conv_x(const float* __restrict__ x,
                                              __hip_bfloat16* __restrict__ xb) {
    const int idx = blockIdx.x * 256 + threadIdx.x;      // 0..262143
    const float4* xp = reinterpret_cast<const float4*>(x) + 2 * idx;
    float4 a = xp[0], b = xp[1];
    uint4 st;
    st.x = cvtpk(a.x, a.y);
    st.y = cvtpk(a.z, a.w);
    st.z = cvtpk(b.x, b.y);
    st.w = cvtpk(b.z, b.w);
    reinterpret_cast<uint4*>(xb)[idx] = st;
}

// ---------------------------------------------------------------------------
// Convert + transpose weights: wt[n][k] = w_attn[k][n], wpt[n][k] = w_proj[k][n]
// ---------------------------------------------------------------------------
__global__ __launch_bounds__(256) void conv_w(const float* __restrict__ wa,
                                              const float* __restrict__ wp,
                                              __hip_bfloat16* __restrict__ wt,
                                              __hip_bfloat16* __restrict__ wpt) {
    const int tid = blockIdx.x * 256 + threadIdx.x;      // 0..65535
    if (tid < 384 * 128) {
        const int n = tid >> 7, k = tid & 127;
        wt[tid] = __float2bfloat16(wa[k * 384 + n]);
    } else {
        const int t2 = tid - 384 * 128;
        const int n = t2 >> 7, k = t2 & 127;
        wpt[t2] = __float2bfloat16(wp[k * 128 + n]);
    }
}

// ---------------------------------------------------------------------------
// QKV GEMM (MFMA bf16): [16384,128] @ [128,384].
// Block = 4 waves; wave = 64M x 32N tile; wave index == head.
// Scatters Q (pre-scaled), K into [BH][S][HD]; V transposed into [BH][HD][S].
// ---------------------------------------------------------------------------
__global__ __launch_bounds__(256) void qkv_mfma(const __hip_bfloat16* __restrict__ xb,
                                                const __hip_bfloat16* __restrict__ wt,
                                                __hip_bfloat16* __restrict__ Qb,
                                                __hip_bfloat16* __restrict__ Kb,
                                                __hip_bfloat16* __restrict__ Vt) {
    const int mt   = blockIdx.x & 255;           // m-tile; XCD = mt%8 for all 3 nblk
    const int nblk = blockIdx.x >> 8;            // 0..2 -> which of Q/K/V
    const int wave = threadIdx.x >> 6;           // 0..3 == head
    const int lane = threadIdx.x & 63;
    const int lq   = lane & 31;
    const int hi   = lane >> 5;

    const int m0 = mt * 64;
    const __hip_bfloat16* a0p = xb + (m0 + lq) * 128 + 8 * hi;
    const __hip_bfloat16* a1p = a0p + 32 * 128;
    const __hip_bfloat16* bp  = wt + ((nblk * 128 + wave * 32) + lq) * 128 + 8 * hi;

    f32x16 acc0 = {}, acc1 = {};
#pragma unroll
    for (int ks = 0; ks < 8; ++ks) {
        bf16x8 bf = ld8(bp + 16 * ks);
        bf16x8 af0 = ld8(a0p + 16 * ks);
        bf16x8 af1 = ld8(a1p + 16 * ks);
        acc0 = __builtin_amdgcn_mfma_f32_32x32x16_bf16(af0, bf, acc0, 0, 0, 0);
        acc1 = __builtin_amdgcn_mfma_f32_32x32x16_bf16(af1, bf, acc1, 0, 0, 0);
    }

    const int b  = m0 >> 11;
    const int s0 = m0 & (S_ - 1);
    const int bh = b * H_ + wave;                // head == wave

    if (nblk == 0) {
        const float qs = 0.2550052557342824f;    // 1/sqrt(32) * log2(e)
#pragma unroll
        for (int r = 0; r < 16; ++r) {
            const int row = (r & 3) + 8 * (r >> 2) + 4 * hi;
            Qb[(bh * S_ + s0 + row) * HD_ + lq]      = __float2bfloat16(acc0[r] * qs);
            Qb[(bh * S_ + s0 + 32 + row) * HD_ + lq] = __float2bfloat16(acc1[r] * qs);
        }
    } else if (nblk == 1) {
#pragma unroll
        for (int r = 0; r < 16; ++r) {
            const int row = (r & 3) + 8 * (r >> 2) + 4 * hi;
            Kb[(bh * S_ + s0 + row) * HD_ + lq]      = __float2bfloat16(acc0[r]);
            Kb[(bh * S_ + s0 + 32 + row) * HD_ + lq] = __float2bfloat16(acc1[r]);
        }
    } else {
        __hip_bfloat16* vbase = Vt + (bh * HD_ + lq) * S_ + s0;
#pragma unroll
        for (int g = 0; g < 4; ++g) {
            union { __hip_bfloat16 h[4]; ushort4 u; } p0, p1;
#pragma unroll
            for (int j = 0; j < 4; ++j) {
                p0.h[j] = __float2bfloat16(acc0[4 * g + j]);
                p1.h[j] = __float2bfloat16(acc1[4 * g + j]);
            }
            *reinterpret_cast<ushort4*>(vbase + 8 * g + 4 * hi)      = p0.u;
            *reinterpret_cast<ushort4*>(vbase + 32 + 8 * g + 4 * hi) = p1.u;
        }
    }
}

// ---------------------------------------------------------------------------
// MFMA causal flash attention (1 wave = 32 q-rows). Writes bf16 output.
// ---------------------------------------------------------------------------
__global__ __launch_bounds__(64) void fattn_kernel(
    const __hip_bfloat16* __restrict__ Qb,
    const __hip_bfloat16* __restrict__ Kb,
    const __hip_bfloat16* __restrict__ Vt,
    __hip_bfloat16* __restrict__ AOb)            // [B][S][D] bf16
{
    const int bh   = blockIdx.x & 31;            // head h -> XCD h%8
    const int qt   = blockIdx.x >> 5;            // 0..63
    const int lane = threadIdx.x;
    const int lq   = lane & 31;
    const int hi   = lane >> 5;
    const int q0   = qt * 32;

    const __hip_bfloat16* qrow = Qb + (bh * S_ + q0 + lq) * HD_ + 8 * hi;
    const bf16x8 qf0 = ld8(qrow);
    const bf16x8 qf1 = ld8(qrow + 16);

    const __hip_bfloat16* kp = Kb + bh * S_ * HD_ + lq * HD_ + 8 * hi;
    const __hip_bfloat16* vp = Vt + (bh * HD_ + lq) * S_ + 8 * hi;

    f32x16 oacc = {};
    float m = -1e30f, lsum = 0.f;
    const int nt = qt + 1;

    bf16x8 kf0 = ld8(kp), kf1 = ld8(kp + 16);
    bf16x8 vf0 = ld8(vp), vf1 = ld8(vp + 16);

    for (int t = 0; t < nt; ++t) {
        const bf16x8 ck0 = kf0, ck1 = kf1, cv0 = vf0, cv1 = vf1;
        if (t + 1 < nt) {
            const __hip_bfloat16* kn = kp + (t + 1) * 32 * HD_;
            const __hip_bfloat16* vn = vp + (t + 1) * 32;
            kf0 = ld8(kn); kf1 = ld8(kn + 16);
            vf0 = ld8(vn); vf1 = ld8(vn + 16);
        }

        f32x16 s = {};
        s = __builtin_amdgcn_mfma_f32_32x32x16_bf16(ck0, qf0, s, 0, 0, 0);
        s = __builtin_amdgcn_mfma_f32_32x32x16_bf16(ck1, qf1, s, 0, 0, 0);

        if (t == qt) {
#pragma unroll
            for (int r = 0; r < 16; ++r) {
                const int kloc = (r & 3) + 8 * (r >> 2) + 4 * hi;
                s[r] = (kloc > lq) ? -1e30f : s[r];
            }
        }

        float tmax = s[0];
#pragma unroll
        for (int r = 1; r < 16; ++r) tmax = fmaxf(tmax, s[r]);
        tmax = fmaxf(tmax, __shfl_xor(tmax, 32));
        const float mnew = fmaxf(m, tmax);
        const float corr = __builtin_amdgcn_exp2f(m - mnew);
        m = mnew;
        lsum *= corr;
#pragma unroll
        for (int r = 0; r < 16; ++r) oacc[r] *= corr;

#pragma unroll
        for (int r = 0; r < 16; ++r) {
            s[r] = __builtin_amdgcn_exp2f(s[r] - m);
            lsum += s[r];
        }

        unsigned a0 = cvtpk(s[0], s[1]),   a1 = cvtpk(s[2], s[3]);
        unsigned a2 = cvtpk(s[4], s[5]),   a3 = cvtpk(s[6], s[7]);
        swap32(a0, a2); swap32(a1, a3);
        unsigned b0 = cvtpk(s[8], s[9]),   b1 = cvtpk(s[10], s[11]);
        unsigned b2 = cvtpk(s[12], s[13]), b3 = cvtpk(s[14], s[15]);
        swap32(b0, b2); swap32(b1, b3);

        union { unsigned u[4]; bf16x8 v; } pb0, pb1;
        pb0.u[0] = a0; pb0.u[1] = a1; pb0.u[2] = a2; pb0.u[3] = a3;
        pb1.u[0] = b0; pb1.u[1] = b1; pb1.u[2] = b2; pb1.u[3] = b3;

        oacc = __builtin_amdgcn_mfma_f32_32x32x16_bf16(cv0, pb0.v, oacc, 0, 0, 0);
        oacc = __builtin_amdgcn_mfma_f32_32x32x16_bf16(cv1, pb1.v, oacc, 0, 0, 0);
    }

    lsum += __shfl_xor(lsum, 32);
    const float inv = 1.f / lsum;
    const int b = bh >> 2, h = bh & 3;
    __hip_bfloat16* orow = AOb + (b * S_ + q0 + lq) * D_ + h * HD_;
#pragma unroll
    for (int g = 0; g < 4; ++g) {
        union { __hip_bfloat16 h[4]; ushort4 u; } st;
#pragma unroll
        for (int j = 0; j < 4; ++j) st.h[j] = __float2bfloat16(oacc[4 * g + j] * inv);
        *reinterpret_cast<ushort4*>(orow + 8 * g + 4 * hi) = st.u;
    }
}

// ---------------------------------------------------------------------------
// Projection GEMM (MFMA bf16): [16384,128] @ [128,128] -> fp32 out.
// Block = 4 waves covering 64M x 128N.
// ---------------------------------------------------------------------------
__global__ __launch_bounds__(256) void proj_mfma(const __hip_bfloat16* __restrict__ AOb,
                                                 const __hip_bfloat16* __restrict__ wpt,
                                                 float* __restrict__ out) {
    const int wave = threadIdx.x >> 6;
    const int lane = threadIdx.x & 63;
    const int lq   = lane & 31;
    const int hi   = lane >> 5;

    const int m0 = blockIdx.x * 64;
    const int n0 = wave * 32;
    const __hip_bfloat16* a0p = AOb + (m0 + lq) * 128 + 8 * hi;
    const __hip_bfloat16* a1p = a0p + 32 * 128;
    const __hip_bfloat16* bp  = wpt + (n0 + lq) * 128 + 8 * hi;

    f32x16 acc0 = {}, acc1 = {};
#pragma unroll
    for (int ks = 0; ks < 8; ++ks) {
        bf16x8 bf = ld8(bp + 16 * ks);
        bf16x8 af0 = ld8(a0p + 16 * ks);
        bf16x8 af1 = ld8(a1p + 16 * ks);
        acc0 = __builtin_amdgcn_mfma_f32_32x32x16_bf16(af0, bf, acc0, 0, 0, 0);
        acc1 = __builtin_amdgcn_mfma_f32_32x32x16_bf16(af1, bf, acc1, 0, 0, 0);
    }

#pragma unroll
    for (int r = 0; r < 16; ++r) {
        const int row = (r & 3) + 8 * (r >> 2) + 4 * hi;
        out[(m0 + row) * 128 + n0 + lq]      = acc0[r];
        out[(m0 + 32 + row) * 128 + n0 + lq] = acc1[r];
    }
}

// ---------------------------------------------------------------------------
extern "C" void kernel_launch(void* const* d_in, const int* in_sizes, int n_in,
                              void* d_out, int out_size, void* d_ws, size_t ws_size,
                              hipStream_t stream) {
    const float* x      = (const float*)d_in[0];
    const float* w_attn = (const float*)d_in[1];
    const float* w_proj = (const float*)d_in[2];
    float* out = (float*)d_out;

    char* ws = (char*)d_ws;
    __hip_bfloat16* Qb  = (__hip_bfloat16*)(ws);                     // 4 MB
    __hip_bfloat16* Kb  = (__hip_bfloat16*)(ws + (4  << 20));        // 4 MB
    __hip_bfloat16* Vt  = (__hip_bfloat16*)(ws + (8  << 20));        // 4 MB
    __hip_bfloat16* AOb = (__hip_bfloat16*)(ws + (12 << 20));        // 4 MB
    __hip_bfloat16* xb  = (__hip_bfloat16*)(ws + (16 << 20));        // 4 MB
    __hip_bfloat16* wt  = (__hip_bfloat16*)(ws + (20 << 20));        // 96 KB
    __hip_bfloat16* wpt = (__hip_bfloat16*)(ws + (20 << 20) + (128 << 10)); // 32 KB

    conv_x<<<1024, 256, 0, stream>>>(x, xb);
    conv_w<<<256, 256, 0, stream>>>(w_attn, w_proj, wt, wpt);
    qkv_mfma<<<768, 256, 0, stream>>>(xb, wt, Qb, Kb, Vt);
    fattn_kernel<<<BH_ * (S_ / 32), 64, 0, stream>>>(Qb, Kb, Vt, AOb);
    proj_mfma<<<256, 256, 0, stream>>>(AOb, wpt, out);
}

// Round 4
// 62.637 us; speedup vs baseline: 10.8028x; 1.0933x over previous
//
#include <hip/hip_runtime.h>
#include <hip/hip_bf16.h>

#define B_  8
#define S_  2048
#define D_  128
#define H_  4
#define HD_ 32
#define BH_ (B_ * H_)

typedef __bf16 bf16x8 __attribute__((ext_vector_type(8)));
typedef float f32x16 __attribute__((ext_vector_type(16)));

__device__ inline bf16x8 ld8(const __hip_bfloat16* p) {
    return *reinterpret_cast<const bf16x8*>(p);
}
__device__ inline unsigned cvtpk(float lo, float hi) {
    unsigned r;
    asm("v_cvt_pk_bf16_f32 %0, %1, %2" : "=v"(r) : "v"(lo), "v"(hi));
    return r;
}
__device__ inline void swap32(unsigned &a, unsigned &b) {
    asm("v_permlane32_swap_b32 %0, %1" : "+v"(a), "+v"(b));
}
__device__ inline float ex2(float x) { return __builtin_amdgcn_exp2f(x); }

// ---------------------------------------------------------------------------
// Weight convert+transpose via LDS tiles (coalesced both sides).
// blocks 0..47: w_attn (128x384 -> wt[384][128]); 48..63: w_proj -> wpt[128][128]
// ---------------------------------------------------------------------------
__global__ __launch_bounds__(256) void conv_w(const float* __restrict__ wa,
                                              const float* __restrict__ wp,
                                              __hip_bfloat16* __restrict__ wt,
                                              __hip_bfloat16* __restrict__ wpt) {
    __shared__ float tile[32][33];
    int bid = blockIdx.x;
    const float* src;
    __hip_bfloat16* dst;
    int N, k0, n0;
    if (bid < 48) { src = wa; dst = wt;  N = 384; k0 = (bid / 12) * 32; n0 = (bid % 12) * 32; }
    else { bid -= 48; src = wp; dst = wpt; N = 128; k0 = (bid / 4) * 32; n0 = (bid % 4) * 32; }
    const int r = threadIdx.x >> 5, c = threadIdx.x & 31;
#pragma unroll
    for (int j = 0; j < 4; ++j)
        tile[r + 8 * j][c] = src[(k0 + r + 8 * j) * N + n0 + c];
    __syncthreads();
#pragma unroll
    for (int j = 0; j < 4; ++j)
        dst[(n0 + r + 8 * j) * 128 + k0 + c] = __float2bfloat16(tile[c][r + 8 * j]);
}

// ---------------------------------------------------------------------------
// QKV GEMM, fused fp32->bf16 convert of x. Block = 4 waves (wave == head),
// m-tile = 32 rows. Each wave: 3 independent MFMA chains (Q,K,V).
// ---------------------------------------------------------------------------
__global__ __launch_bounds__(256) void qkv_mfma(const float* __restrict__ x,
                                                const __hip_bfloat16* __restrict__ wt,
                                                __hip_bfloat16* __restrict__ Qb,
                                                __hip_bfloat16* __restrict__ Kb,
                                                __hip_bfloat16* __restrict__ Vt) {
    const int mt   = blockIdx.x;                 // 0..511
    const int wave = threadIdx.x >> 6;           // head
    const int lane = threadIdx.x & 63;
    const int lq   = lane & 31;
    const int hi   = lane >> 5;
    const int m0   = mt * 32;

    const float* ax = x + (m0 + lq) * 128 + 8 * hi;
    const __hip_bfloat16* bq = wt + ((      wave * 32) + lq) * 128 + 8 * hi;
    const __hip_bfloat16* bk = wt + ((128 + wave * 32) + lq) * 128 + 8 * hi;
    const __hip_bfloat16* bv = wt + ((256 + wave * 32) + lq) * 128 + 8 * hi;

    f32x16 aq = {}, ak = {}, av = {};
#pragma unroll
    for (int ks = 0; ks < 8; ++ks) {
        float4 x0 = *reinterpret_cast<const float4*>(ax + 16 * ks);
        float4 x1 = *reinterpret_cast<const float4*>(ax + 16 * ks + 4);
        union { unsigned u[4]; bf16x8 v; } af;
        af.u[0] = cvtpk(x0.x, x0.y); af.u[1] = cvtpk(x0.z, x0.w);
        af.u[2] = cvtpk(x1.x, x1.y); af.u[3] = cvtpk(x1.z, x1.w);
        aq = __builtin_amdgcn_mfma_f32_32x32x16_bf16(af.v, ld8(bq + 16 * ks), aq, 0, 0, 0);
        ak = __builtin_amdgcn_mfma_f32_32x32x16_bf16(af.v, ld8(bk + 16 * ks), ak, 0, 0, 0);
        av = __builtin_amdgcn_mfma_f32_32x32x16_bf16(af.v, ld8(bv + 16 * ks), av, 0, 0, 0);
    }

    const int b  = m0 >> 11;
    const int s0 = m0 & (S_ - 1);
    const int bh = b * H_ + wave;
    const float qs = 0.2550052557342824f;        // 1/sqrt(32) * log2(e)

#pragma unroll
    for (int r = 0; r < 16; ++r) {
        const int row = (r & 3) + 8 * (r >> 2) + 4 * hi;
        Qb[(bh * S_ + s0 + row) * HD_ + lq] = __float2bfloat16(aq[r] * qs);
        Kb[(bh * S_ + s0 + row) * HD_ + lq] = __float2bfloat16(ak[r]);
    }
    __hip_bfloat16* vbase = Vt + (bh * HD_ + lq) * S_ + s0;
#pragma unroll
    for (int g = 0; g < 4; ++g) {
        union { __hip_bfloat16 h[4]; ushort4 u; } pv;
#pragma unroll
        for (int j = 0; j < 4; ++j) pv.h[j] = __float2bfloat16(av[4 * g + j]);
        *reinterpret_cast<ushort4*>(vbase + 8 * g + 4 * hi) = pv.u;
    }
}

// ---------------------------------------------------------------------------
// MFMA causal flash attention. Block = 256 thr = 4 waves, one 32-q tile.
// Wave wv handles k-tiles t = wv, wv+4, ...; partials combined in LDS.
// qt dispatch order reversed (longest first). Defer-max (T13).
// ---------------------------------------------------------------------------
__global__ __launch_bounds__(256) void fattn_kernel(
    const __hip_bfloat16* __restrict__ Qb,
    const __hip_bfloat16* __restrict__ Kb,
    const __hip_bfloat16* __restrict__ Vt,
    __hip_bfloat16* __restrict__ AOb)
{
    const int bh   = blockIdx.x & 31;            // head h -> XCD spread
    const int qt   = 63 - (blockIdx.x >> 5);     // longest blocks first
    const int wv   = threadIdx.x >> 6;           // k-split 0..3
    const int lane = threadIdx.x & 63;
    const int lq   = lane & 31;
    const int hi   = lane >> 5;
    const int q0   = qt * 32;
    const int nt   = qt + 1;

    __shared__ float Ol[4][32][33];
    __shared__ float Ml[4][32];
    __shared__ float Ll[4][32];

    const __hip_bfloat16* qrow = Qb + (bh * S_ + q0 + lq) * HD_ + 8 * hi;
    const bf16x8 qf0 = ld8(qrow);
    const bf16x8 qf1 = ld8(qrow + 16);

    const __hip_bfloat16* kp = Kb + bh * S_ * HD_ + lq * HD_ + 8 * hi;
    const __hip_bfloat16* vp = Vt + (bh * HD_ + lq) * S_ + 8 * hi;

    f32x16 oacc = {};
    float m = -1e30f, lsum = 0.f;

    bf16x8 kf0 = ld8(kp + wv * 32 * HD_), kf1 = ld8(kp + wv * 32 * HD_ + 16);
    bf16x8 vf0 = ld8(vp + wv * 32),       vf1 = ld8(vp + wv * 32 + 16);

    for (int t = wv; t < nt; t += 4) {
        const bf16x8 ck0 = kf0, ck1 = kf1, cv0 = vf0, cv1 = vf1;
        if (t + 4 < nt) {
            const __hip_bfloat16* kn = kp + (t + 4) * 32 * HD_;
            const __hip_bfloat16* vn = vp + (t + 4) * 32;
            kf0 = ld8(kn); kf1 = ld8(kn + 16);
            vf0 = ld8(vn); vf1 = ld8(vn + 16);
        }

        f32x16 s = {};
        s = __builtin_amdgcn_mfma_f32_32x32x16_bf16(ck0, qf0, s, 0, 0, 0);
        s = __builtin_amdgcn_mfma_f32_32x32x16_bf16(ck1, qf1, s, 0, 0, 0);

        if (t == qt) {                           // diagonal: mask k>q
#pragma unroll
            for (int r = 0; r < 16; ++r) {
                const int kloc = (r & 3) + 8 * (r >> 2) + 4 * hi;
                s[r] = (kloc > lq) ? -1e30f : s[r];
            }
        }

        // max3-friendly reduction tree
        float a = fmaxf(fmaxf(s[0], s[1]), s[2]);
        float bb = fmaxf(fmaxf(s[3], s[4]), s[5]);
        float c = fmaxf(fmaxf(s[6], s[7]), s[8]);
        float d = fmaxf(fmaxf(s[9], s[10]), s[11]);
        float e = fmaxf(fmaxf(s[12], s[13]), s[14]);
        float tmax = fmaxf(fmaxf(fmaxf(a, bb), c), fmaxf(fmaxf(d, e), s[15]));
        tmax = fmaxf(tmax, __shfl_xor(tmax, 32));

        if (__any(tmax > m + 8.f)) {             // T13 defer-max
            const float mnew = fmaxf(m, tmax);
            const float corr = ex2(m - mnew);
            lsum *= corr;
#pragma unroll
            for (int r = 0; r < 16; ++r) oacc[r] *= corr;
            m = mnew;
        }

#pragma unroll
        for (int r = 0; r < 16; ++r) s[r] = ex2(s[r] - m);
        // pairwise sum tree
        {
            float p0 = (s[0] + s[1]) + (s[2] + s[3]);
            float p1 = (s[4] + s[5]) + (s[6] + s[7]);
            float p2 = (s[8] + s[9]) + (s[10] + s[11]);
            float p3 = (s[12] + s[13]) + (s[14] + s[15]);
            lsum += (p0 + p1) + (p2 + p3);
        }

        unsigned a0 = cvtpk(s[0], s[1]),   a1 = cvtpk(s[2], s[3]);
        unsigned a2 = cvtpk(s[4], s[5]),   a3 = cvtpk(s[6], s[7]);
        swap32(a0, a2); swap32(a1, a3);
        unsigned b0 = cvtpk(s[8], s[9]),   b1 = cvtpk(s[10], s[11]);
        unsigned b2 = cvtpk(s[12], s[13]), b3 = cvtpk(s[14], s[15]);
        swap32(b0, b2); swap32(b1, b3);

        union { unsigned u[4]; bf16x8 v; } pb0, pb1;
        pb0.u[0] = a0; pb0.u[1] = a1; pb0.u[2] = a2; pb0.u[3] = a3;
        pb1.u[0] = b0; pb1.u[1] = b1; pb1.u[2] = b2; pb1.u[3] = b3;

        oacc = __builtin_amdgcn_mfma_f32_32x32x16_bf16(cv0, pb0.v, oacc, 0, 0, 0);
        oacc = __builtin_amdgcn_mfma_f32_32x32x16_bf16(cv1, pb1.v, oacc, 0, 0, 0);
    }

    lsum += __shfl_xor(lsum, 32);

#pragma unroll
    for (int r = 0; r < 16; ++r) {
        const int d = (r & 3) + 8 * (r >> 2) + 4 * hi;
        Ol[wv][lq][d] = oacc[r];
    }
    if (hi == 0) { Ml[wv][lq] = m; Ll[wv][lq] = lsum; }
    __syncthreads();

    // combine 4 partials: tid -> (q, 4 d's)
    const int q  = threadIdx.x >> 3;
    const int d0 = (threadIdx.x & 7) * 4;
    const float m0_ = Ml[0][q], m1_ = Ml[1][q], m2_ = Ml[2][q], m3_ = Ml[3][q];
    const float ms = fmaxf(fmaxf(m0_, m1_), fmaxf(m2_, m3_));
    const float f0 = ex2(m0_ - ms), f1 = ex2(m1_ - ms);
    const float f2 = ex2(m2_ - ms), f3 = ex2(m3_ - ms);
    const float lst = f0 * Ll[0][q] + f1 * Ll[1][q] + f2 * Ll[2][q] + f3 * Ll[3][q];
    const float inv = 1.f / lst;

    const int b = bh >> 2, h = bh & 3;
    union { __hip_bfloat16 h4[4]; ushort4 u; } st;
#pragma unroll
    for (int j = 0; j < 4; ++j) {
        const float o = f0 * Ol[0][q][d0 + j] + f1 * Ol[1][q][d0 + j] +
                        f2 * Ol[2][q][d0 + j] + f3 * Ol[3][q][d0 + j];
        st.h4[j] = __float2bfloat16(o * inv);
    }
    *reinterpret_cast<ushort4*>(AOb + (b * S_ + q0 + q) * D_ + h * HD_ + d0) = st.u;
}

// ---------------------------------------------------------------------------
// Projection GEMM: [16384,128]x[128,128] -> fp32. m-tile 32, 4 waves (n-split).
// ---------------------------------------------------------------------------
__global__ __launch_bounds__(256) void proj_mfma(const __hip_bfloat16* __restrict__ AOb,
                                                 const __hip_bfloat16* __restrict__ wpt,
                                                 float* __restrict__ out) {
    const int m0   = blockIdx.x * 32;
    const int wave = threadIdx.x >> 6;
    const int lane = threadIdx.x & 63;
    const int lq   = lane & 31;
    const int hi   = lane >> 5;
    const int n0   = wave * 32;

    const __hip_bfloat16* ap = AOb + (m0 + lq) * 128 + 8 * hi;
    const __hip_bfloat16* bp = wpt + (n0 + lq) * 128 + 8 * hi;

    f32x16 acc = {};
#pragma unroll
    for (int ks = 0; ks < 8; ++ks)
        acc = __builtin_amdgcn_mfma_f32_32x32x16_bf16(ld8(ap + 16 * ks), ld8(bp + 16 * ks), acc, 0, 0, 0);

#pragma unroll
    for (int r = 0; r < 16; ++r) {
        const int row = (r & 3) + 8 * (r >> 2) + 4 * hi;
        out[(m0 + row) * 128 + n0 + lq] = acc[r];
    }
}

// ---------------------------------------------------------------------------
extern "C" void kernel_launch(void* const* d_in, const int* in_sizes, int n_in,
                              void* d_out, int out_size, void* d_ws, size_t ws_size,
                              hipStream_t stream) {
    const float* x      = (const float*)d_in[0];
    const float* w_attn = (const float*)d_in[1];
    const float* w_proj = (const float*)d_in[2];
    float* out = (float*)d_out;

    char* ws = (char*)d_ws;
    __hip_bfloat16* Qb  = (__hip_bfloat16*)(ws);                     // 4 MB
    __hip_bfloat16* Kb  = (__hip_bfloat16*)(ws + (4  << 20));        // 4 MB
    __hip_bfloat16* Vt  = (__hip_bfloat16*)(ws + (8  << 20));        // 4 MB
    __hip_bfloat16* AOb = (__hip_bfloat16*)(ws + (12 << 20));        // 4 MB
    __hip_bfloat16* wt  = (__hip_bfloat16*)(ws + (16 << 20));        // 96 KB
    __hip_bfloat16* wpt = (__hip_bfloat16*)(ws + (16 << 20) + (128 << 10)); // 32 KB

    conv_w<<<64, 256, 0, stream>>>(w_attn, w_proj, wt, wpt);
    qkv_mfma<<<512, 256, 0, stream>>>(x, wt, Qb, Kb, Vt);
    fattn_kernel<<<BH_ * (S_ / 32), 256, 0, stream>>>(Qb, Kb, Vt, AOb);
    proj_mfma<<<512, 256, 0, stream>>>(AOb, wpt, out);
}

// Round 5
// 61.717 us; speedup vs baseline: 10.9639x; 1.0149x over previous
//
#include <hip/hip_runtime.h>
#include <hip/hip_bf16.h>

#define B_  8
#define S_  2048
#define D_  128
#define H_  4
#define HD_ 32
#define BH_ (B_ * H_)

typedef __bf16 bf16x8 __attribute__((ext_vector_type(8)));
typedef float f32x16 __attribute__((ext_vector_type(16)));

__device__ inline bf16x8 ld8(const __hip_bfloat16* p) {
    return *reinterpret_cast<const bf16x8*>(p);
}
__device__ inline unsigned cvtpk(float lo, float hi) {
    unsigned r;
    asm("v_cvt_pk_bf16_f32 %0, %1, %2" : "=v"(r) : "v"(lo), "v"(hi));
    return r;
}
__device__ inline void swap32(unsigned &a, unsigned &b) {
    asm("v_permlane32_swap_b32 %0, %1" : "+v"(a), "+v"(b));
}
__device__ inline float ex2(float x) { return __builtin_amdgcn_exp2f(x); }

// ---------------------------------------------------------------------------
// Weight convert+transpose via LDS tiles (coalesced both sides).
// blocks 0..47: w_attn -> wt[384][128]; 48..63: w_proj -> wpt[128][128]
// ---------------------------------------------------------------------------
__global__ __launch_bounds__(256) void conv_w(const float* __restrict__ wa,
                                              const float* __restrict__ wp,
                                              __hip_bfloat16* __restrict__ wt,
                                              __hip_bfloat16* __restrict__ wpt) {
    __shared__ float tile[32][33];
    int bid = blockIdx.x;
    const float* src;
    __hip_bfloat16* dst;
    int N, k0, n0;
    if (bid < 48) { src = wa; dst = wt;  N = 384; k0 = (bid / 12) * 32; n0 = (bid % 12) * 32; }
    else { bid -= 48; src = wp; dst = wpt; N = 128; k0 = (bid / 4) * 32; n0 = (bid % 4) * 32; }
    const int r = threadIdx.x >> 5, c = threadIdx.x & 31;
#pragma unroll
    for (int j = 0; j < 4; ++j)
        tile[r + 8 * j][c] = src[(k0 + r + 8 * j) * N + n0 + c];
    __syncthreads();
#pragma unroll
    for (int j = 0; j < 4; ++j)
        dst[(n0 + r + 8 * j) * 128 + k0 + c] = __float2bfloat16(tile[c][r + 8 * j]);
}

// ---------------------------------------------------------------------------
// QKV GEMM, fused fp32->bf16 convert of x. Block = 4 waves (wave == head),
// m-tile = 32 rows. Depth-2 software pipeline on x and B fragment loads.
// ---------------------------------------------------------------------------
__global__ __launch_bounds__(256) void qkv_mfma(const float* __restrict__ x,
                                                const __hip_bfloat16* __restrict__ wt,
                                                __hip_bfloat16* __restrict__ Qb,
                                                __hip_bfloat16* __restrict__ Kb,
                                                __hip_bfloat16* __restrict__ Vt) {
    const int mt   = blockIdx.x;                 // 0..511
    const int wave = threadIdx.x >> 6;           // head
    const int lane = threadIdx.x & 63;
    const int lq   = lane & 31;
    const int hi   = lane >> 5;
    const int m0   = mt * 32;

    const float* ax = x + (m0 + lq) * 128 + 8 * hi;
    const __hip_bfloat16* bq = wt + ((      wave * 32) + lq) * 128 + 8 * hi;
    const __hip_bfloat16* bk = wt + ((128 + wave * 32) + lq) * 128 + 8 * hi;
    const __hip_bfloat16* bv = wt + ((256 + wave * 32) + lq) * 128 + 8 * hi;

    f32x16 aq = {}, ak = {}, av = {};

    // depth-2 pipeline
    float4 x0a = *reinterpret_cast<const float4*>(ax);
    float4 x1a = *reinterpret_cast<const float4*>(ax + 4);
    bf16x8 bqa = ld8(bq), bka = ld8(bk), bva = ld8(bv);
    float4 x0b = *reinterpret_cast<const float4*>(ax + 16);
    float4 x1b = *reinterpret_cast<const float4*>(ax + 20);
    bf16x8 bqb = ld8(bq + 16), bkb = ld8(bk + 16), bvb = ld8(bv + 16);

#pragma unroll
    for (int ks = 0; ks < 8; ++ks) {
        const float4 cx0 = x0a, cx1 = x1a;
        const bf16x8 cbq = bqa, cbk = bka, cbv = bva;
        x0a = x0b; x1a = x1b; bqa = bqb; bka = bkb; bva = bvb;
        if (ks < 6) {
            x0b = *reinterpret_cast<const float4*>(ax + 16 * (ks + 2));
            x1b = *reinterpret_cast<const float4*>(ax + 16 * (ks + 2) + 4);
            bqb = ld8(bq + 16 * (ks + 2));
            bkb = ld8(bk + 16 * (ks + 2));
            bvb = ld8(bv + 16 * (ks + 2));
        }
        union { unsigned u[4]; bf16x8 v; } af;
        af.u[0] = cvtpk(cx0.x, cx0.y); af.u[1] = cvtpk(cx0.z, cx0.w);
        af.u[2] = cvtpk(cx1.x, cx1.y); af.u[3] = cvtpk(cx1.z, cx1.w);
        aq = __builtin_amdgcn_mfma_f32_32x32x16_bf16(af.v, cbq, aq, 0, 0, 0);
        ak = __builtin_amdgcn_mfma_f32_32x32x16_bf16(af.v, cbk, ak, 0, 0, 0);
        av = __builtin_amdgcn_mfma_f32_32x32x16_bf16(af.v, cbv, av, 0, 0, 0);
    }

    const int b  = m0 >> 11;
    const int s0 = m0 & (S_ - 1);
    const int bh = b * H_ + wave;
    const float qs = 0.2550052557342824f;        // 1/sqrt(32) * log2(e)

#pragma unroll
    for (int r = 0; r < 16; ++r) {
        const int row = (r & 3) + 8 * (r >> 2) + 4 * hi;
        Qb[(bh * S_ + s0 + row) * HD_ + lq] = __float2bfloat16(aq[r] * qs);
        Kb[(bh * S_ + s0 + row) * HD_ + lq] = __float2bfloat16(ak[r]);
    }
    __hip_bfloat16* vbase = Vt + (bh * HD_ + lq) * S_ + s0;
#pragma unroll
    for (int g = 0; g < 4; ++g) {
        union { __hip_bfloat16 h[4]; ushort4 u; } pv;
#pragma unroll
        for (int j = 0; j < 4; ++j) pv.h[j] = __float2bfloat16(av[4 * g + j]);
        *reinterpret_cast<ushort4*>(vbase + 8 * g + 4 * hi) = pv.u;
    }
}

// ---------------------------------------------------------------------------
// MFMA causal flash attention. Block = 4 waves, one 32-q tile; wave wv does
// k-tiles t = wv, wv+4, ... with 2-deep register prefetch; LDS combine.
// ---------------------------------------------------------------------------
__global__ __launch_bounds__(256) void fattn_kernel(
    const __hip_bfloat16* __restrict__ Qb,
    const __hip_bfloat16* __restrict__ Kb,
    const __hip_bfloat16* __restrict__ Vt,
    __hip_bfloat16* __restrict__ AOb)
{
    const int bh   = blockIdx.x & 31;            // head -> XCD spread
    const int qt   = 63 - (blockIdx.x >> 5);     // longest blocks first
    const int wv   = threadIdx.x >> 6;           // k-split 0..3
    const int lane = threadIdx.x & 63;
    const int lq   = lane & 31;
    const int hi   = lane >> 5;
    const int q0   = qt * 32;
    const int nt   = qt + 1;

    __shared__ float Ol[4][32][33];
    __shared__ float Ml[4][32];
    __shared__ float Ll[4][32];

    const __hip_bfloat16* qrow = Qb + (bh * S_ + q0 + lq) * HD_ + 8 * hi;
    const bf16x8 qf0 = ld8(qrow);
    const bf16x8 qf1 = ld8(qrow + 16);

    const __hip_bfloat16* kp = Kb + bh * S_ * HD_ + lq * HD_ + 8 * hi;
    const __hip_bfloat16* vp = Vt + (bh * HD_ + lq) * S_ + 8 * hi;

    f32x16 oacc = {};
    float m = -1e30f, lsum = 0.f;

    // 2-deep prefetch: set A = iter t, set B = iter t+4
    bf16x8 k0a = {}, k1a = {}, v0a = {}, v1a = {};
    bf16x8 k0b = {}, k1b = {}, v0b = {}, v1b = {};
    if (wv < nt) {
        k0a = ld8(kp + wv * 32 * HD_); k1a = ld8(kp + wv * 32 * HD_ + 16);
        v0a = ld8(vp + wv * 32);       v1a = ld8(vp + wv * 32 + 16);
    }
    if (wv + 4 < nt) {
        k0b = ld8(kp + (wv + 4) * 32 * HD_); k1b = ld8(kp + (wv + 4) * 32 * HD_ + 16);
        v0b = ld8(vp + (wv + 4) * 32);       v1b = ld8(vp + (wv + 4) * 32 + 16);
    }

    for (int t = wv; t < nt; t += 4) {
        const bf16x8 ck0 = k0a, ck1 = k1a, cv0 = v0a, cv1 = v1a;
        k0a = k0b; k1a = k1b; v0a = v0b; v1a = v1b;
        if (t + 8 < nt) {                        // issue loads 2 iters ahead
            const __hip_bfloat16* kn = kp + (t + 8) * 32 * HD_;
            const __hip_bfloat16* vn = vp + (t + 8) * 32;
            k0b = ld8(kn); k1b = ld8(kn + 16);
            v0b = ld8(vn); v1b = ld8(vn + 16);
        }

        __builtin_amdgcn_s_setprio(1);
        f32x16 s = {};
        s = __builtin_amdgcn_mfma_f32_32x32x16_bf16(ck0, qf0, s, 0, 0, 0);
        s = __builtin_amdgcn_mfma_f32_32x32x16_bf16(ck1, qf1, s, 0, 0, 0);
        __builtin_amdgcn_s_setprio(0);

        if (t == qt) {                           // diagonal: mask k>q
#pragma unroll
            for (int r = 0; r < 16; ++r) {
                const int kloc = (r & 3) + 8 * (r >> 2) + 4 * hi;
                s[r] = (kloc > lq) ? -1e30f : s[r];
            }
        }

        float a = fmaxf(fmaxf(s[0], s[1]), s[2]);
        float bb = fmaxf(fmaxf(s[3], s[4]), s[5]);
        float c = fmaxf(fmaxf(s[6], s[7]), s[8]);
        float d = fmaxf(fmaxf(s[9], s[10]), s[11]);
        float e = fmaxf(fmaxf(s[12], s[13]), s[14]);
        float tmax = fmaxf(fmaxf(fmaxf(a, bb), c), fmaxf(fmaxf(d, e), s[15]));
        tmax = fmaxf(tmax, __shfl_xor(tmax, 32));

        if (__any(tmax > m + 8.f)) {             // T13 defer-max
            const float mnew = fmaxf(m, tmax);
            const float corr = ex2(m - mnew);
            lsum *= corr;
#pragma unroll
            for (int r = 0; r < 16; ++r) oacc[r] *= corr;
            m = mnew;
        }

#pragma unroll
        for (int r = 0; r < 16; ++r) s[r] = ex2(s[r] - m);
        {
            float p0 = (s[0] + s[1]) + (s[2] + s[3]);
            float p1 = (s[4] + s[5]) + (s[6] + s[7]);
            float p2 = (s[8] + s[9]) + (s[10] + s[11]);
            float p3 = (s[12] + s[13]) + (s[14] + s[15]);
            lsum += (p0 + p1) + (p2 + p3);
        }

        unsigned a0 = cvtpk(s[0], s[1]),   a1 = cvtpk(s[2], s[3]);
        unsigned a2 = cvtpk(s[4], s[5]),   a3 = cvtpk(s[6], s[7]);
        swap32(a0, a2); swap32(a1, a3);
        unsigned b0 = cvtpk(s[8], s[9]),   b1 = cvtpk(s[10], s[11]);
        unsigned b2 = cvtpk(s[12], s[13]), b3 = cvtpk(s[14], s[15]);
        swap32(b0, b2); swap32(b1, b3);

        union { unsigned u[4]; bf16x8 v; } pb0, pb1;
        pb0.u[0] = a0; pb0.u[1] = a1; pb0.u[2] = a2; pb0.u[3] = a3;
        pb1.u[0] = b0; pb1.u[1] = b1; pb1.u[2] = b2; pb1.u[3] = b3;

        __builtin_amdgcn_s_setprio(1);
        oacc = __builtin_amdgcn_mfma_f32_32x32x16_bf16(cv0, pb0.v, oacc, 0, 0, 0);
        oacc = __builtin_amdgcn_mfma_f32_32x32x16_bf16(cv1, pb1.v, oacc, 0, 0, 0);
        __builtin_amdgcn_s_setprio(0);
    }

    lsum += __shfl_xor(lsum, 32);

#pragma unroll
    for (int r = 0; r < 16; ++r) {
        const int d = (r & 3) + 8 * (r >> 2) + 4 * hi;
        Ol[wv][lq][d] = oacc[r];
    }
    if (hi == 0) { Ml[wv][lq] = m; Ll[wv][lq] = lsum; }
    __syncthreads();

    const int q  = threadIdx.x >> 3;
    const int d0 = (threadIdx.x & 7) * 4;
    const float m0_ = Ml[0][q], m1_ = Ml[1][q], m2_ = Ml[2][q], m3_ = Ml[3][q];
    const float ms = fmaxf(fmaxf(m0_, m1_), fmaxf(m2_, m3_));
    const float f0 = ex2(m0_ - ms), f1 = ex2(m1_ - ms);
    const float f2 = ex2(m2_ - ms), f3 = ex2(m3_ - ms);
    const float lst = f0 * Ll[0][q] + f1 * Ll[1][q] + f2 * Ll[2][q] + f3 * Ll[3][q];
    const float inv = 1.f / lst;

    const int b = bh >> 2, h = bh & 3;
    union { __hip_bfloat16 h4[4]; ushort4 u; } st;
#pragma unroll
    for (int j = 0; j < 4; ++j) {
        const float o = f0 * Ol[0][q][d0 + j] + f1 * Ol[1][q][d0 + j] +
                        f2 * Ol[2][q][d0 + j] + f3 * Ol[3][q][d0 + j];
        st.h4[j] = __float2bfloat16(o * inv);
    }
    *reinterpret_cast<ushort4*>(AOb + (b * S_ + q0 + q) * D_ + h * HD_ + d0) = st.u;
}

// ---------------------------------------------------------------------------
// Projection GEMM: [16384,128]x[128,128] -> fp32. All 16 frag loads hoisted.
// ---------------------------------------------------------------------------
__global__ __launch_bounds__(256) void proj_mfma(const __hip_bfloat16* __restrict__ AOb,
                                                 const __hip_bfloat16* __restrict__ wpt,
                                                 float* __restrict__ out) {
    const int m0   = blockIdx.x * 32;
    const int wave = threadIdx.x >> 6;
    const int lane = threadIdx.x & 63;
    const int lq   = lane & 31;
    const int hi   = lane >> 5;
    const int n0   = wave * 32;

    const __hip_bfloat16* ap = AOb + (m0 + lq) * 128 + 8 * hi;
    const __hip_bfloat16* bp = wpt + (n0 + lq) * 128 + 8 * hi;

    bf16x8 A[8], Bf[8];
#pragma unroll
    for (int ks = 0; ks < 8; ++ks) {
        A[ks]  = ld8(ap + 16 * ks);
        Bf[ks] = ld8(bp + 16 * ks);
    }

    f32x16 acc = {};
#pragma unroll
    for (int ks = 0; ks < 8; ++ks)
        acc = __builtin_amdgcn_mfma_f32_32x32x16_bf16(A[ks], Bf[ks], acc, 0, 0, 0);

#pragma unroll
    for (int r = 0; r < 16; ++r) {
        const int row = (r & 3) + 8 * (r >> 2) + 4 * hi;
        out[(m0 + row) * 128 + n0 + lq] = acc[r];
    }
}

// ---------------------------------------------------------------------------
extern "C" void kernel_launch(void* const* d_in, const int* in_sizes, int n_in,
                              void* d_out, int out_size, void* d_ws, size_t ws_size,
                              hipStream_t stream) {
    const float* x      = (const float*)d_in[0];
    const float* w_attn = (const float*)d_in[1];
    const float* w_proj = (const float*)d_in[2];
    float* out = (float*)d_out;

    char* ws = (char*)d_ws;
    __hip_bfloat16* Qb  = (__hip_bfloat16*)(ws);                     // 4 MB
    __hip_bfloat16* Kb  = (__hip_bfloat16*)(ws + (4  << 20));        // 4 MB
    __hip_bfloat16* Vt  = (__hip_bfloat16*)(ws + (8  << 20));        // 4 MB
    __hip_bfloat16* AOb = (__hip_bfloat16*)(ws + (12 << 20));        // 4 MB
    __hip_bfloat16* wt  = (__hip_bfloat16*)(ws + (16 << 20));        // 96 KB
    __hip_bfloat16* wpt = (__hip_bfloat16*)(ws + (16 << 20) + (128 << 10)); // 32 KB

    conv_w<<<64, 256, 0, stream>>>(w_attn, w_proj, wt, wpt);
    qkv_mfma<<<512, 256, 0, stream>>>(x, wt, Qb, Kb, Vt);
    fattn_kernel<<<BH_ * (S_ / 32), 256, 0, stream>>>(Qb, Kb, Vt, AOb);
    proj_mfma<<<512, 256, 0, stream>>>(AOb, wpt, out);
}